// Round 12
// baseline (246.733 us; speedup 1.0000x reference)
//
#include <hip/hip_runtime.h>
#include <cstdint>

#define TDIM 1024
#define BDIM 4
#define EPSF 1e-6f

// ---- workspace layout ----
#define OFF_KSUM  32768u      // [32,16,64]   raw per-chunk k sums
#define OFF_KV    65536u      // [32,16,64,64] raw per-chunk kv sums
#define FLOAT_BYTES 8650752u  // 2,162,688 floats
#define UOFF_QP 0u            // q proj bf16 [4096,512]
#define UOFF_KP 2097152u
#define UOFF_VP 4194304u
#define UOFF_NB 6291456u      // normalized numerator bf16 [4096,512]
#define UOFF_WQ 8388608u      // transposed weights [n][k] bf16, 512x512 each
#define UOFF_WK 8650752u
#define UOFF_WV 8912896u
#define UOFF_WG 9175040u
#define UOFF_WO 9437184u

typedef short bf16x8 __attribute__((ext_vector_type(8)));
typedef float f32x4  __attribute__((ext_vector_type(4)));
typedef unsigned short ushort_t;

union bfu { int4 i4; unsigned short us[8]; bf16x8 v; };

__device__ __forceinline__ float phi_f(float x)  { return x > 0.f ? x + 1.f : __expf(x); }
__device__ __forceinline__ float sigm_f(float x) { return 1.f / (1.f + __expf(-x)); }
__device__ __forceinline__ unsigned short f2b(float x) {
    union { float f; unsigned u; } v; v.f = x;
    return (unsigned short)((v.u + 0x7FFFu + ((v.u >> 16) & 1u)) >> 16);
}
__device__ __forceinline__ float b2f(unsigned short s) {
    union { unsigned u; float f; } v; v.u = (unsigned)s << 16; return v.f;
}
__device__ __forceinline__ int4 pack8(float4 a, float4 b) {
    bfu u;
    u.us[0] = f2b(a.x); u.us[1] = f2b(a.y); u.us[2] = f2b(a.z); u.us[3] = f2b(a.w);
    u.us[4] = f2b(b.x); u.us[5] = f2b(b.y); u.us[6] = f2b(b.z); u.us[7] = f2b(b.w);
    return u.i4;
}
#define FMA4(ACC, S, V) do { (ACC).x += (S)*(V).x; (ACC).y += (S)*(V).y; \
                             (ACC).z += (S)*(V).z; (ACC).w += (S)*(V).w; } while (0)

// ---------------------------------------------------------------------------
// cast + transpose all 5 weights: W[512 k][512 n] fp32 -> Wt[512 n][512 k] bf16
// ---------------------------------------------------------------------------
__global__ __launch_bounds__(256) void castwt_all(const float* __restrict__ W0,
                                                  const float* __restrict__ W1,
                                                  const float* __restrict__ W2,
                                                  const float* __restrict__ W3,
                                                  const float* __restrict__ W4,
                                                  ushort_t* __restrict__ T0,
                                                  ushort_t* __restrict__ T1,
                                                  ushort_t* __restrict__ T2,
                                                  ushort_t* __restrict__ T3,
                                                  ushort_t* __restrict__ T4) {
    const float* W; ushort_t* Wt;
    switch (blockIdx.z) {
        case 0: W = W0; Wt = T0; break;
        case 1: W = W1; Wt = T1; break;
        case 2: W = W2; Wt = T2; break;
        case 3: W = W3; Wt = T3; break;
        default: W = W4; Wt = T4; break;
    }
    __shared__ unsigned short tile[32][36];
    const int t = threadIdx.x;
    const int r0 = blockIdx.y * 32, c0 = blockIdx.x * 32;
    {
        const int r = t >> 3, c4 = (t & 7) * 4;
        float4 x = *(const float4*)(W + (size_t)(r0 + r) * 512 + c0 + c4);
        tile[c4 + 0][r] = f2b(x.x); tile[c4 + 1][r] = f2b(x.y);
        tile[c4 + 2][r] = f2b(x.z); tile[c4 + 3][r] = f2b(x.w);
    }
    __syncthreads();
    const int c = t >> 3, r4 = (t & 7) * 4;
    ushort4 o;
    o.x = tile[c][r4 + 0]; o.y = tile[c][r4 + 1];
    o.z = tile[c][r4 + 2]; o.w = tile[c][r4 + 3];
    *(ushort4*)(Wt + (size_t)(c0 + c) * 512 + r0 + r4) = o;
}

// ---------------------------------------------------------------------------
// Fused projection GEMM, grid (64,8,4) — uniform work per block (8 MFMA/step)
// ---------------------------------------------------------------------------
__global__ __launch_bounds__(256) void proj_k(const float* __restrict__ query,
                                              const float* __restrict__ key_,
                                              const float* __restrict__ value,
                                              const ushort_t* __restrict__ wqt,
                                              const ushort_t* __restrict__ wkt,
                                              const ushort_t* __restrict__ wvt,
                                              const ushort_t* __restrict__ wgt,
                                              const float* __restrict__ bg,
                                              ushort_t* __restrict__ qp,
                                              ushort_t* __restrict__ kp,
                                              ushort_t* __restrict__ vp) {
    __shared__ __align__(16) unsigned short As[2][4096];
    __shared__ __align__(16) unsigned short Bs[2][4096];
    __shared__ __align__(16) unsigned short Bs2[2][2048];
    const int z = blockIdx.z;
    const bool dual = (z >= 2);
    const float* A = (z == 0) ? query : (z == 1) ? key_ : value;
    const ushort_t* B0 = (z == 0) ? wqt : (z == 1) ? wkt : wvt;
    ushort_t* outp = (z == 0) ? qp : (z == 1) ? kp : vp;

    const int tid = threadIdx.x;
    const int row0 = blockIdx.x * 64, n0 = blockIdx.y * 64;
    const int nbase = dual ? (n0 + (z - 2) * 32) : n0;
    const int w = tid >> 6, lane = tid & 63;
    const int cc = tid & 7, rr = tid >> 3;
    const int fm = lane & 15, fq = lane >> 4;
    const int la0 = (cc * 64 + (rr ^ cc)) * 8;
    const int la1 = (cc * 64 + ((rr + 32) ^ cc)) * 8;
    const int lg0 = (cc * 32 + (rr ^ cc)) * 8;

    f32x4 acc[4], acc2[2];
#pragma unroll
    for (int i = 0; i < 4; i++) acc[i] = (f32x4){0.f, 0.f, 0.f, 0.f};
#pragma unroll
    for (int i = 0; i < 2; i++) acc2[i] = (f32x4){0.f, 0.f, 0.f, 0.f};

    const float*    aptr = A   + (size_t)(row0 + rr) * 512 + cc * 8;
    const ushort_t* bptr = B0  + (size_t)(nbase + rr) * 512 + cc * 8;
    const ushort_t* gptr = wgt + (size_t)(nbase + rr) * 512 + cc * 8;

    float4 a0 = *(const float4*)(aptr);
    float4 a1 = *(const float4*)(aptr + 4);
    float4 a2 = *(const float4*)(aptr + 32 * 512);
    float4 a3 = *(const float4*)(aptr + 32 * 512 + 4);
    int4 b0 = *(const int4*)(bptr);
    int4 b1 = {0, 0, 0, 0}, g0 = {0, 0, 0, 0};
    if (dual) g0 = *(const int4*)(gptr);
    else      b1 = *(const int4*)(bptr + 32 * 512);
    *(int4*)&As[0][la0] = pack8(a0, a1);
    *(int4*)&As[0][la1] = pack8(a2, a3);
    *(int4*)&Bs[0][la0] = b0;
    if (dual) *(int4*)&Bs2[0][lg0] = g0;
    else      *(int4*)&Bs[0][la1] = b1;
    __syncthreads();

    for (int kti = 0; kti < 8; kti++) {
        const int buf = kti & 1;
        if (kti < 7) {
            const int off = (kti + 1) * 64;
            a0 = *(const float4*)(aptr + off);
            a1 = *(const float4*)(aptr + off + 4);
            a2 = *(const float4*)(aptr + off + 32 * 512);
            a3 = *(const float4*)(aptr + off + 32 * 512 + 4);
            b0 = *(const int4*)(bptr + off);
            if (dual) g0 = *(const int4*)(gptr + off);
            else      b1 = *(const int4*)(bptr + off + 32 * 512);
        }
        if (dual) {
#pragma unroll
            for (int j = 0; j < 2; j++) {
                const int cu = j * 4 + fq;
                bf16x8 af = *(const bf16x8*)&As[buf][(cu * 64 + ((w * 16 + fm) ^ cu)) * 8];
#pragma unroll
                for (int nb = 0; nb < 2; nb++) {
                    bf16x8 bv = *(const bf16x8*)&Bs[buf][(cu * 64 + ((nb * 16 + fm) ^ cu)) * 8];
                    bf16x8 gv = *(const bf16x8*)&Bs2[buf][(cu * 32 + ((nb * 16 + fm) ^ cu)) * 8];
                    acc[nb]  = __builtin_amdgcn_mfma_f32_16x16x32_bf16(af, bv, acc[nb], 0, 0, 0);
                    acc2[nb] = __builtin_amdgcn_mfma_f32_16x16x32_bf16(af, gv, acc2[nb], 0, 0, 0);
                }
            }
        } else {
#pragma unroll
            for (int j = 0; j < 2; j++) {
                const int cu = j * 4 + fq;
                bf16x8 af = *(const bf16x8*)&As[buf][(cu * 64 + ((w * 16 + fm) ^ cu)) * 8];
#pragma unroll
                for (int nb = 0; nb < 4; nb++) {
                    bf16x8 bv = *(const bf16x8*)&Bs[buf][(cu * 64 + ((nb * 16 + fm) ^ cu)) * 8];
                    acc[nb] = __builtin_amdgcn_mfma_f32_16x16x32_bf16(af, bv, acc[nb], 0, 0, 0);
                }
            }
        }
        if (kti < 7) {
            const int nb_ = buf ^ 1;
            *(int4*)&As[nb_][la0] = pack8(a0, a1);
            *(int4*)&As[nb_][la1] = pack8(a2, a3);
            *(int4*)&Bs[nb_][la0] = b0;
            if (dual) *(int4*)&Bs2[nb_][lg0] = g0;
            else      *(int4*)&Bs[nb_][la1] = b1;
            __syncthreads();
        }
    }

    if (dual) {
#pragma unroll
        for (int nb = 0; nb < 2; nb++) {
            const int col = nbase + nb * 16 + fm;
            const float bb = bg[col];
#pragma unroll
            for (int r = 0; r < 4; r++) {
                const int row = row0 + w * 16 + fq * 4 + r;
                outp[(size_t)row * 512 + col] =
                    f2b(acc[nb][r] * 2.f * sigm_f(acc2[nb][r] + bb));
            }
        }
    } else {
#pragma unroll
        for (int nb = 0; nb < 4; nb++) {
            const int col = n0 + nb * 16 + fm;
#pragma unroll
            for (int r = 0; r < 4; r++) {
                const int row = row0 + w * 16 + fq * 4 + r;
                outp[(size_t)row * 512 + col] = f2b(phi_f(acc[nb][r]));
            }
        }
    }
}

// ---------------------------------------------------------------------------
// Output projection: out[4096,512] fp32 = nb(bf16) @ Wo^T, double-buffered
// ---------------------------------------------------------------------------
__global__ __launch_bounds__(256) void outproj_k(const ushort_t* __restrict__ A,
                                                 const ushort_t* __restrict__ Bt,
                                                 float* __restrict__ out) {
    __shared__ __align__(16) unsigned short As[2][4096];
    __shared__ __align__(16) unsigned short Bs[2][4096];
    const int tid = threadIdx.x;
    const int row0 = blockIdx.x * 64, n0 = blockIdx.y * 64;
    const int w = tid >> 6, lane = tid & 63;
    const int cc = tid & 7, rr = tid >> 3;
    const int fm = lane & 15, fq = lane >> 4;
    const int la0 = (cc * 64 + (rr ^ cc)) * 8;
    const int la1 = (cc * 64 + ((rr + 32) ^ cc)) * 8;

    f32x4 acc[4];
#pragma unroll
    for (int i = 0; i < 4; i++) acc[i] = (f32x4){0.f, 0.f, 0.f, 0.f};

    const ushort_t* aptr = A  + (size_t)(row0 + rr) * 512 + cc * 8;
    const ushort_t* bptr = Bt + (size_t)(n0 + rr) * 512 + cc * 8;
    int4 ra0 = *(const int4*)(aptr);
    int4 ra1 = *(const int4*)(aptr + 32 * 512);
    int4 rb0 = *(const int4*)(bptr);
    int4 rb1 = *(const int4*)(bptr + 32 * 512);
    *(int4*)&As[0][la0] = ra0; *(int4*)&As[0][la1] = ra1;
    *(int4*)&Bs[0][la0] = rb0; *(int4*)&Bs[0][la1] = rb1;
    __syncthreads();

    for (int kti = 0; kti < 8; kti++) {
        const int buf = kti & 1;
        if (kti < 7) {
            const int off = (kti + 1) * 64;
            ra0 = *(const int4*)(aptr + off);
            ra1 = *(const int4*)(aptr + off + 32 * 512);
            rb0 = *(const int4*)(bptr + off);
            rb1 = *(const int4*)(bptr + off + 32 * 512);
        }
#pragma unroll
        for (int j = 0; j < 2; j++) {
            const int cu = j * 4 + fq;
            bf16x8 af = *(const bf16x8*)&As[buf][(cu * 64 + ((w * 16 + fm) ^ cu)) * 8];
#pragma unroll
            for (int nb = 0; nb < 4; nb++) {
                bf16x8 bv = *(const bf16x8*)&Bs[buf][(cu * 64 + ((nb * 16 + fm) ^ cu)) * 8];
                acc[nb] = __builtin_amdgcn_mfma_f32_16x16x32_bf16(af, bv, acc[nb], 0, 0, 0);
            }
        }
        if (kti < 7) {
            const int nb_ = buf ^ 1;
            *(int4*)&As[nb_][la0] = ra0; *(int4*)&As[nb_][la1] = ra1;
            *(int4*)&Bs[nb_][la0] = rb0; *(int4*)&Bs[nb_][la1] = rb1;
            __syncthreads();
        }
    }
#pragma unroll
    for (int nb = 0; nb < 4; nb++) {
        const int col = n0 + nb * 16 + fm;
#pragma unroll
        for (int r = 0; r < 4; r++) {
            const int row = row0 + w * 16 + fq * 4 + r;
            __builtin_nontemporal_store(acc[nb][r], &out[(size_t)row * 512 + col]);
        }
    }
}

// ---------------------------------------------------------------------------
// K2a: per-(b,h,chunk) RAW sums: kv[k][v] = sum_t kf[t][k]*vg[t][v]; ksum[k]
// ---------------------------------------------------------------------------
__global__ __launch_bounds__(256) void chunksum_k(const ushort_t* __restrict__ kb,
                                                  const ushort_t* __restrict__ vb,
                                                  float* __restrict__ kv,
                                                  float* __restrict__ ksum) {
    __shared__ __align__(16) float kf_c[64][68];
    __shared__ __align__(16) float vg_c[64][68];
    const int tid = threadIdx.x;
    const int bh = blockIdx.x, c = blockIdx.y;
    const int b = bh >> 3, h = bh & 7;
    const int r = tid >> 2, qq = tid & 3;
    {
        const size_t rowbase = ((size_t)(b * TDIM + c * 64 + r)) * 512 + h * 64 + qq * 16;
        bfu k0, k1, v0, v1;
        k0.i4 = *(const int4*)(kb + rowbase);
        k1.i4 = *(const int4*)(kb + rowbase + 8);
        v0.i4 = *(const int4*)(vb + rowbase);
        v1.i4 = *(const int4*)(vb + rowbase + 8);
#pragma unroll
        for (int j = 0; j < 8; j++) {
            kf_c[r][qq * 16 + j]     = b2f(k0.us[j]);
            kf_c[r][qq * 16 + 8 + j] = b2f(k1.us[j]);
            vg_c[r][qq * 16 + j]     = b2f(v0.us[j]);
            vg_c[r][qq * 16 + 8 + j] = b2f(v1.us[j]);
        }
    }
    __syncthreads();
    const int k0i = (tid >> 4) * 4;
    const int v0i = (tid & 15) * 4;
    float4 a4[4];
#pragma unroll
    for (int i = 0; i < 4; i++) a4[i] = make_float4(0.f, 0.f, 0.f, 0.f);
    for (int t = 0; t < 64; t++) {
        float4 kk4 = *(const float4*)&kf_c[t][k0i];
        float4 vv  = *(const float4*)&vg_c[t][v0i];
        FMA4(a4[0], kk4.x, vv); FMA4(a4[1], kk4.y, vv);
        FMA4(a4[2], kk4.z, vv); FMA4(a4[3], kk4.w, vv);
    }
    const size_t base = (size_t)(bh * 16 + c) * 64;
#pragma unroll
    for (int i = 0; i < 4; i++)
        *(float4*)(kv + (base + k0i + i) * 64 + v0i) = a4[i];
    if (tid < 64) {
        float s = 0.f;
        for (int t = 0; t < 64; t++) s += kf_c[t][tid];
        ksum[base + tid] = s;
    }
}

// ---------------------------------------------------------------------------
// FUSED, 2-way s-split: grid (32 bh, 16 diag, 2 z).
// z=0: heavy state (kvc prefix, numer->nbo) + att tiles s in [0, split)
// z=1: light state (Q/K-diag/ksum only; no kvc, no V, no numer) + att tiles
//      s in [split, diag) + diag tile + zero-fill.
// inv_s computed identically in both (same ops/inputs) -> no cross-block dep.
// LDS diet to 53248 B (52 KB) -> 3 blocks/CU (12 waves/CU vs 8):
//   sc stored bf16 (P3 consumed it as bf16 anyway; denom sums same bf16);
//   vrow aliases K-stream buffer 1 (vrow dies at P3; kb1 first written at
//   stream start from registers held since P1).
// ---------------------------------------------------------------------------
__global__ __launch_bounds__(256, 3) void fused_k(const ushort_t* __restrict__ qb,
                                                  const ushort_t* __restrict__ kb,
                                                  const ushort_t* __restrict__ vb,
                                                  const float* __restrict__ kvc,
                                                  const float* __restrict__ ksum,
                                                  ushort_t* __restrict__ nbo,
                                                  float* __restrict__ att) {
    extern __shared__ __align__(16) char smem[];
    unsigned short* qs    = (unsigned short*)smem;              // [0,8192)
    unsigned short* ksb   = qs + 4096;                          // 2 x 8KB [8192,24576)
    unsigned short* vrow  = (unsigned short*)(smem + 16384);    // alias ksb buf1, 64x72 [16384,25600)
    unsigned short* sc16  = (unsigned short*)(smem + 25600);    // 64x68 bf16 [25600,34304)
    float* kvf   = (float*)(smem + 34304);                      // 64x68 f32 [34304,51712)
    float* kpre  = (float*)(smem + 51712);                      // 64
    float* ps    = (float*)(smem + 51968);                      // 256
    float* inv_s = (float*)(smem + 52992);                      // 64

    const int tid = threadIdx.x;
    const int bh = blockIdx.x;
    const int yy = (int)blockIdx.y;
    const int diag = (yy < 8) ? (15 - yy) : (yy - 8);
    const bool zlight = (blockIdx.z != 0);
    const int split = (2 * diag) / 5;
    const int s_begin = zlight ? split : 0;
    const int s_end   = zlight ? diag  : split;
    const int tt0 = diag * 64;
    const int b = bh >> 3, h = bh & 7;
    const int w = tid >> 6, lane = tid & 63;
    const int fm = lane & 15, fq = lane >> 4;
    const int rr = tid >> 3, cc = tid & 7;
    const int la0 = (cc * 64 + (rr ^ cc)) * 8;
    const int la1 = (cc * 64 + ((rr + 32) ^ cc)) * 8;

    const ushort_t* kbase = kb + ((size_t)(b * TDIM + rr)) * 512 + h * 64 + cc * 8;

    // ---- P0: staging ----
    {
        const ushort_t* qptr = qb + ((size_t)(b * TDIM + tt0 + rr)) * 512 + h * 64 + cc * 8;
        *(int4*)&qs[la0] = *(const int4*)qptr;
        *(int4*)&qs[la1] = *(const int4*)(qptr + 32 * 512);
        const ushort_t* kptr = kbase + (size_t)tt0 * 512;
        *(int4*)&ksb[la0] = *(const int4*)kptr;
        *(int4*)&ksb[la1] = *(const int4*)(kptr + 32 * 512);
        const int r = tid >> 2, qq = tid & 3;
        if (!zlight) {
            // V rows coalesced (vrow aliases ksb buf1 region — safe until stream)
            const ushort_t* vptr = vb + ((size_t)(b * TDIM + tt0 + r)) * 512 + h * 64 + qq * 16;
            *(int4*)&vrow[r * 72 + qq * 16]     = *(const int4*)vptr;
            *(int4*)&vrow[r * 72 + qq * 16 + 8] = *(const int4*)(vptr + 8);
            // KVpre accumulate over raw chunk sums
            float4 a4[4];
#pragma unroll
            for (int u = 0; u < 4; u++) a4[u] = make_float4(0.f, 0.f, 0.f, 0.f);
            for (int c2 = 0; c2 < diag; c2++) {
                const float* p = kvc + (size_t)(bh * 16 + c2) * 4096 + r * 64 + qq * 16;
#pragma unroll
                for (int u = 0; u < 4; u++) {
                    float4 x = *(const float4*)(p + 4 * u);
                    a4[u].x += x.x; a4[u].y += x.y; a4[u].z += x.z; a4[u].w += x.w;
                }
            }
#pragma unroll
            for (int u = 0; u < 4; u++) *(float4*)&kvf[r * 68 + qq * 16 + 4 * u] = a4[u];
        }
        if (tid < 64) {
            float s = 0.f;
            for (int c2 = 0; c2 < diag; c2++)
                s += ksum[(size_t)(bh * 16 + c2) * 64 + tid];
            kpre[tid] = s;
        }
    }
    __syncthreads();

    // ---- P1: diag S = Q.K^T (sa in regs); issue stream-chunk prefetch ----
    f32x4 sa[4];
    int4 rk0 = {0, 0, 0, 0}, rk1 = {0, 0, 0, 0};
    {
        if (s_end > s_begin) {
            const size_t off = (size_t)s_begin * 64 * 512;
            rk0 = *(const int4*)(kbase + off);
            rk1 = *(const int4*)(kbase + off + 32 * 512);
        }
#pragma unroll
        for (int i = 0; i < 4; i++) sa[i] = (f32x4){0.f, 0.f, 0.f, 0.f};
#pragma unroll
        for (int j = 0; j < 2; j++) {
            const int cu = j * 4 + fq;
            bf16x8 aqf = *(const bf16x8*)&qs[(cu * 64 + ((w * 16 + fm) ^ cu)) * 8];
#pragma unroll
            for (int nb = 0; nb < 4; nb++) {
                bf16x8 bk = *(const bf16x8*)&ksb[(cu * 64 + ((nb * 16 + fm) ^ cu)) * 8];
                sa[nb] = __builtin_amdgcn_mfma_f32_16x16x32_bf16(aqf, bk, sa[nb], 0, 0, 0);
            }
        }
#pragma unroll
        for (int nb = 0; nb < 4; nb++) {
            const int s_l = nb * 16 + fm;
#pragma unroll
            for (int r = 0; r < 4; r++) {
                const int t_l = w * 16 + fq * 4 + r;
                sc16[t_l * 68 + s_l] = (s_l <= t_l) ? f2b(sa[nb][r]) : (unsigned short)0;
            }
        }
    }
    __syncthreads();

    // ---- P2: denom -> inv_s (sc16 is bf16) ----
    {
        const int rw = tid >> 2, sq = tid & 3;
        float p = 0.f;
#pragma unroll
        for (int s = sq * 16; s < sq * 16 + 16; s++) p += b2f(sc16[rw * 68 + s]);
#pragma unroll
        for (int kd = sq * 16; kd < sq * 16 + 16; kd++) {
            const int cu = kd >> 3;
            p += b2f(qs[(cu * 64 + (rw ^ cu)) * 8 + (kd & 7)]) * kpre[kd];
        }
        ps[rw * 4 + sq] = p;
    }
    __syncthreads();
    {
        const int rw = tid >> 2, sq = tid & 3;
        if (sq == 0) {
            float den = ps[rw * 4] + ps[rw * 4 + 1] + ps[rw * 4 + 2] + ps[rw * 4 + 3];
            inv_s[rw] = 1.f / (den + EPSF);
        }
    }
    __syncthreads();

    float invr[4];
#pragma unroll
    for (int r = 0; r < 4; r++) invr[r] = inv_s[w * 16 + fq * 4 + r];
    float* attb = att + (size_t)bh * TDIM * TDIM;

    if (!zlight) {
        // ---- P3: numer = Q.KVpre^T + P.V^T, scaled; write nbo bf16 ----
        f32x4 oa[4];
#pragma unroll
        for (int i = 0; i < 4; i++) oa[i] = (f32x4){0.f, 0.f, 0.f, 0.f};
        bf16x8 aqv[2], apv[2];
#pragma unroll
        for (int j = 0; j < 2; j++) {
            const int cu = j * 4 + fq;
            aqv[j] = *(const bf16x8*)&qs[(cu * 64 + ((w * 16 + fm) ^ cu)) * 8];
            bfu t;
#pragma unroll
            for (int e2 = 0; e2 < 8; e2++) t.us[e2] = sc16[(w * 16 + fm) * 68 + cu * 8 + e2];
            apv[j] = t.v;
        }
#pragma unroll
        for (int nb = 0; nb < 4; nb++) {
            const int v = nb * 16 + fm;
#pragma unroll
            for (int j = 0; j < 2; j++) {
                const int cu = j * 4 + fq;
                bfu tkv, tv;
#pragma unroll
                for (int e = 0; e < 8; e++) {
                    tkv.us[e] = f2b(kvf[(cu * 8 + e) * 68 + v]);
                    tv.us[e]  = vrow[(cu * 8 + e) * 72 + v];
                }
                oa[nb] = __builtin_amdgcn_mfma_f32_16x16x32_bf16(aqv[j], tkv.v, oa[nb], 0, 0, 0);
                oa[nb] = __builtin_amdgcn_mfma_f32_16x16x32_bf16(apv[j], tv.v, oa[nb], 0, 0, 0);
            }
        }
#pragma unroll
        for (int nb = 0; nb < 4; nb++) {
            const int vcol = nb * 16 + fm;
#pragma unroll
            for (int r = 0; r < 4; r++) {
                const int t_l = w * 16 + fq * 4 + r;
                const float val = oa[nb][r] * inv_s[t_l];
                nbo[((size_t)(b * TDIM + tt0 + t_l)) * 512 + h * 64 + vcol] = f2b(val);
            }
        }
    } else {
        // ---- z=1: diagonal tile (from sa) + zero-fill right of diagonal ----
#pragma unroll
        for (int nb = 0; nb < 4; nb++) {
            const int s_l = nb * 16 + fm;
#pragma unroll
            for (int r = 0; r < 4; r++) {
                const int t_l = w * 16 + fq * 4 + r;
                const float val = (s_l <= t_l) ? sa[nb][r] * invr[r] : 0.f;
                __builtin_nontemporal_store(val,
                    &attb[(size_t)(tt0 + t_l) * TDIM + tt0 + s_l]);
            }
        }
        const f32x4 z = (f32x4){0.f, 0.f, 0.f, 0.f};
        const int r = tid >> 2, qq = tid & 3;
        float* rowp = attb + (size_t)(tt0 + r) * TDIM;
        for (int c0 = (diag + 1) * 64 + qq * 4; c0 < TDIM; c0 += 16)
            __builtin_nontemporal_store(z, (f32x4*)(rowp + c0));
    }

    // ---- P4: att stream over s in [s_begin, s_end) ----
    if (s_end > s_begin) {
        bf16x8 aq[2];
#pragma unroll
        for (int j = 0; j < 2; j++) {
            const int cu = j * 4 + fq;
            aq[j] = *(const bf16x8*)&qs[(cu * 64 + ((w * 16 + fm) ^ cu)) * 8];
        }
        __syncthreads();   // all waves done reading vrow (z0) before kb1 overwrite
        *(int4*)&ksb[4096 + la0] = rk0;
        *(int4*)&ksb[4096 + la1] = rk1;
        __syncthreads();
        int bufsel = 1;
        for (int st = s_begin; st < s_end; ++st, bufsel ^= 1) {
            if (st + 1 < s_end) {
                const size_t off = (size_t)(st + 1) * 64 * 512;
                rk0 = *(const int4*)(kbase + off);
                rk1 = *(const int4*)(kbase + off + 32 * 512);
            }
            f32x4 pa[4];
#pragma unroll
            for (int i = 0; i < 4; i++) pa[i] = (f32x4){0.f, 0.f, 0.f, 0.f};
#pragma unroll
            for (int j = 0; j < 2; j++) {
                const int cu = j * 4 + fq;
#pragma unroll
                for (int nb = 0; nb < 4; nb++) {
                    bf16x8 bk = *(const bf16x8*)&ksb[bufsel * 4096 +
                                                     (cu * 64 + ((nb * 16 + fm) ^ cu)) * 8];
                    pa[nb] = __builtin_amdgcn_mfma_f32_16x16x32_bf16(aq[j], bk, pa[nb], 0, 0, 0);
                }
            }
            const int s0 = st * 64;
#pragma unroll
            for (int nb = 0; nb < 4; nb++) {
                const int s_g = s0 + nb * 16 + fm;
#pragma unroll
                for (int r = 0; r < 4; r++) {
                    const int t_g = tt0 + w * 16 + fq * 4 + r;
                    __builtin_nontemporal_store(pa[nb][r] * invr[r],
                                                &attb[(size_t)t_g * TDIM + s_g]);
                }
            }
            if (st + 1 < s_end) {
                *(int4*)&ksb[(bufsel ^ 1) * 4096 + la0] = rk0;
                *(int4*)&ksb[(bufsel ^ 1) * 4096 + la1] = rk1;
                __syncthreads();
            }
        }
    }
}

// ---------------------------------------------------------------------------
extern "C" void kernel_launch(void* const* d_in, const int* in_sizes, int n_in,
                              void* d_out, int out_size, void* d_ws, size_t ws_size,
                              hipStream_t stream) {
    (void)in_sizes; (void)n_in; (void)out_size; (void)ws_size;
    const float* query = (const float*)d_in[0];
    const float* key   = (const float*)d_in[1];
    const float* value = (const float*)d_in[2];
    const float* Wq    = (const float*)d_in[3];
    const float* Wk    = (const float*)d_in[4];
    const float* Wv    = (const float*)d_in[5];
    const float* Wg    = (const float*)d_in[6];
    const float* bg    = (const float*)d_in[7];
    const float* Wo    = (const float*)d_in[8];
    float* out = (float*)d_out;                  // [B,T,M]
    float* att = (float*)d_out + 2097152;        // [B,H,T,T]
    float* ws  = (float*)d_ws;
    float* ksum = ws + OFF_KSUM;
    float* kv   = ws + OFF_KV;
    ushort_t* ub  = (ushort_t*)((char*)d_ws + FLOAT_BYTES);
    ushort_t* qp  = ub + UOFF_QP;
    ushort_t* kp  = ub + UOFF_KP;
    ushort_t* vp  = ub + UOFF_VP;
    ushort_t* nbp = ub + UOFF_NB;
    ushort_t* wqt = ub + UOFF_WQ;
    ushort_t* wkt = ub + UOFF_WK;
    ushort_t* wvt = ub + UOFF_WV;
    ushort_t* wgt = ub + UOFF_WG;
    ushort_t* wot = ub + UOFF_WO;

    dim3 blk(256);
    castwt_all<<<dim3(16, 16, 5), blk, 0, stream>>>(Wq, Wk, Wv, Wg, Wo,
                                                    wqt, wkt, wvt, wgt, wot);
    proj_k<<<dim3(64, 8, 4), blk, 0, stream>>>(query, key, value,
                                               wqt, wkt, wvt, wgt, bg, qp, kp, vp);
    chunksum_k<<<dim3(32, 16), blk, 0, stream>>>(kp, vp, kv, ksum);
    fused_k<<<dim3(32, 16, 2), blk, 53248, stream>>>(qp, kp, vp, kv, ksum, nbp, att);
    outproj_k<<<dim3(64, 8), blk, 0, stream>>>(nbp, wot, out);
}

// Round 14
// 229.963 us; speedup vs baseline: 1.0729x; 1.0729x over previous
//
#include <hip/hip_runtime.h>
#include <cstdint>

#define TDIM 1024
#define BDIM 4
#define EPSF 1e-6f

// ---- workspace layout ----
#define OFF_KSUM  32768u      // [32,16,64]   raw per-chunk k sums
#define OFF_KV    65536u      // [32,16,64,64] raw per-chunk kv sums
#define FLOAT_BYTES 8650752u  // 2,162,688 floats
#define UOFF_QP 0u            // q proj bf16 [4096,512]
#define UOFF_KP 2097152u
#define UOFF_VP 4194304u
#define UOFF_NB 6291456u      // normalized numerator bf16 [4096,512]
#define UOFF_WQ 8388608u      // transposed weights [n][k] bf16, 512x512 each
#define UOFF_WK 8650752u
#define UOFF_WV 8912896u
#define UOFF_WG 9175040u
#define UOFF_WO 9437184u

typedef short bf16x8 __attribute__((ext_vector_type(8)));
typedef float f32x4  __attribute__((ext_vector_type(4)));
typedef unsigned short ushort_t;

union bfu { int4 i4; unsigned short us[8]; bf16x8 v; };

__device__ __forceinline__ float phi_f(float x)  { return x > 0.f ? x + 1.f : __expf(x); }
__device__ __forceinline__ float sigm_f(float x) { return 1.f / (1.f + __expf(-x)); }
__device__ __forceinline__ unsigned short f2b(float x) {
    union { float f; unsigned u; } v; v.f = x;
    return (unsigned short)((v.u + 0x7FFFu + ((v.u >> 16) & 1u)) >> 16);
}
__device__ __forceinline__ float b2f(unsigned short s) {
    union { unsigned u; float f; } v; v.u = (unsigned)s << 16; return v.f;
}
__device__ __forceinline__ int4 pack8(float4 a, float4 b) {
    bfu u;
    u.us[0] = f2b(a.x); u.us[1] = f2b(a.y); u.us[2] = f2b(a.z); u.us[3] = f2b(a.w);
    u.us[4] = f2b(b.x); u.us[5] = f2b(b.y); u.us[6] = f2b(b.z); u.us[7] = f2b(b.w);
    return u.i4;
}
#define FMA4(ACC, S, V) do { (ACC).x += (S)*(V).x; (ACC).y += (S)*(V).y; \
                             (ACC).z += (S)*(V).z; (ACC).w += (S)*(V).w; } while (0)

// ---------------------------------------------------------------------------
// cast + transpose all 5 weights: W[512 k][512 n] fp32 -> Wt[512 n][512 k] bf16
// ---------------------------------------------------------------------------
__global__ __launch_bounds__(256) void castwt_all(const float* __restrict__ W0,
                                                  const float* __restrict__ W1,
                                                  const float* __restrict__ W2,
                                                  const float* __restrict__ W3,
                                                  const float* __restrict__ W4,
                                                  ushort_t* __restrict__ T0,
                                                  ushort_t* __restrict__ T1,
                                                  ushort_t* __restrict__ T2,
                                                  ushort_t* __restrict__ T3,
                                                  ushort_t* __restrict__ T4) {
    const float* W; ushort_t* Wt;
    switch (blockIdx.z) {
        case 0: W = W0; Wt = T0; break;
        case 1: W = W1; Wt = T1; break;
        case 2: W = W2; Wt = T2; break;
        case 3: W = W3; Wt = T3; break;
        default: W = W4; Wt = T4; break;
    }
    __shared__ unsigned short tile[32][36];
    const int t = threadIdx.x;
    const int r0 = blockIdx.y * 32, c0 = blockIdx.x * 32;
    {
        const int r = t >> 3, c4 = (t & 7) * 4;
        float4 x = *(const float4*)(W + (size_t)(r0 + r) * 512 + c0 + c4);
        tile[c4 + 0][r] = f2b(x.x); tile[c4 + 1][r] = f2b(x.y);
        tile[c4 + 2][r] = f2b(x.z); tile[c4 + 3][r] = f2b(x.w);
    }
    __syncthreads();
    const int c = t >> 3, r4 = (t & 7) * 4;
    ushort4 o;
    o.x = tile[c][r4 + 0]; o.y = tile[c][r4 + 1];
    o.z = tile[c][r4 + 2]; o.w = tile[c][r4 + 3];
    *(ushort4*)(Wt + (size_t)(c0 + c) * 512 + r0 + r4) = o;
}

// ---------------------------------------------------------------------------
// Fused projection GEMM, grid (64,8,3), double-buffered K-loop
// ---------------------------------------------------------------------------
__global__ __launch_bounds__(256) void proj_k(const float* __restrict__ query,
                                              const float* __restrict__ key_,
                                              const float* __restrict__ value,
                                              const ushort_t* __restrict__ wqt,
                                              const ushort_t* __restrict__ wkt,
                                              const ushort_t* __restrict__ wvt,
                                              const ushort_t* __restrict__ wgt,
                                              const float* __restrict__ bg,
                                              ushort_t* __restrict__ qp,
                                              ushort_t* __restrict__ kp,
                                              ushort_t* __restrict__ vp) {
    __shared__ __align__(16) unsigned short As[2][4096];
    __shared__ __align__(16) unsigned short Bs[2][4096];
    __shared__ __align__(16) unsigned short Bs2[2][4096];
    const int z = blockIdx.z;
    const float* A = (z == 0) ? query : (z == 1) ? key_ : value;
    const ushort_t* B0 = (z == 0) ? wqt : (z == 1) ? wkt : wvt;
    ushort_t* outp = (z == 0) ? qp : (z == 1) ? kp : vp;
    const bool dual = (z == 2);

    const int tid = threadIdx.x;
    const int row0 = blockIdx.x * 64, n0 = blockIdx.y * 64;
    const int w = tid >> 6, lane = tid & 63;
    const int cc = tid & 7, rr = tid >> 3;
    const int fm = lane & 15, fq = lane >> 4;
    const int la0 = (cc * 64 + (rr ^ cc)) * 8;
    const int la1 = (cc * 64 + ((rr + 32) ^ cc)) * 8;

    f32x4 acc[4], acc2[4];
#pragma unroll
    for (int i = 0; i < 4; i++) {
        acc[i]  = (f32x4){0.f, 0.f, 0.f, 0.f};
        acc2[i] = (f32x4){0.f, 0.f, 0.f, 0.f};
    }

    const float*   aptr = A  + (size_t)(row0 + rr) * 512 + cc * 8;
    const ushort_t* bptr = B0 + (size_t)(n0 + rr) * 512 + cc * 8;
    const ushort_t* gptr = wgt + (size_t)(n0 + rr) * 512 + cc * 8;

    float4 a0 = *(const float4*)(aptr);
    float4 a1 = *(const float4*)(aptr + 4);
    float4 a2 = *(const float4*)(aptr + 32 * 512);
    float4 a3 = *(const float4*)(aptr + 32 * 512 + 4);
    int4 b0 = *(const int4*)(bptr);
    int4 b1 = *(const int4*)(bptr + 32 * 512);
    int4 g0 = {0, 0, 0, 0}, g1 = {0, 0, 0, 0};
    if (dual) { g0 = *(const int4*)(gptr); g1 = *(const int4*)(gptr + 32 * 512); }
    *(int4*)&As[0][la0] = pack8(a0, a1);
    *(int4*)&As[0][la1] = pack8(a2, a3);
    *(int4*)&Bs[0][la0] = b0; *(int4*)&Bs[0][la1] = b1;
    if (dual) { *(int4*)&Bs2[0][la0] = g0; *(int4*)&Bs2[0][la1] = g1; }
    __syncthreads();

    for (int kti = 0; kti < 8; kti++) {
        const int buf = kti & 1;
        if (kti < 7) {
            const int off = (kti + 1) * 64;
            a0 = *(const float4*)(aptr + off);
            a1 = *(const float4*)(aptr + off + 4);
            a2 = *(const float4*)(aptr + off + 32 * 512);
            a3 = *(const float4*)(aptr + off + 32 * 512 + 4);
            b0 = *(const int4*)(bptr + off);
            b1 = *(const int4*)(bptr + off + 32 * 512);
            if (dual) {
                g0 = *(const int4*)(gptr + off);
                g1 = *(const int4*)(gptr + off + 32 * 512);
            }
        }
        if (dual) {
#pragma unroll
            for (int j = 0; j < 2; j++) {
                const int cu = j * 4 + fq;
                bf16x8 af = *(const bf16x8*)&As[buf][(cu * 64 + ((w * 16 + fm) ^ cu)) * 8];
#pragma unroll
                for (int nb = 0; nb < 4; nb++) {
                    bf16x8 bv = *(const bf16x8*)&Bs[buf][(cu * 64 + ((nb * 16 + fm) ^ cu)) * 8];
                    bf16x8 gv = *(const bf16x8*)&Bs2[buf][(cu * 64 + ((nb * 16 + fm) ^ cu)) * 8];
                    acc[nb]  = __builtin_amdgcn_mfma_f32_16x16x32_bf16(af, bv, acc[nb], 0, 0, 0);
                    acc2[nb] = __builtin_amdgcn_mfma_f32_16x16x32_bf16(af, gv, acc2[nb], 0, 0, 0);
                }
            }
        } else {
#pragma unroll
            for (int j = 0; j < 2; j++) {
                const int cu = j * 4 + fq;
                bf16x8 af = *(const bf16x8*)&As[buf][(cu * 64 + ((w * 16 + fm) ^ cu)) * 8];
#pragma unroll
                for (int nb = 0; nb < 4; nb++) {
                    bf16x8 bv = *(const bf16x8*)&Bs[buf][(cu * 64 + ((nb * 16 + fm) ^ cu)) * 8];
                    acc[nb] = __builtin_amdgcn_mfma_f32_16x16x32_bf16(af, bv, acc[nb], 0, 0, 0);
                }
            }
        }
        if (kti < 7) {
            const int nb_ = buf ^ 1;
            *(int4*)&As[nb_][la0] = pack8(a0, a1);
            *(int4*)&As[nb_][la1] = pack8(a2, a3);
            *(int4*)&Bs[nb_][la0] = b0; *(int4*)&Bs[nb_][la1] = b1;
            if (dual) { *(int4*)&Bs2[nb_][la0] = g0; *(int4*)&Bs2[nb_][la1] = g1; }
            __syncthreads();
        }
    }

#pragma unroll
    for (int nb = 0; nb < 4; nb++) {
        const int col = n0 + nb * 16 + fm;
        const float bb = dual ? bg[col] : 0.f;
#pragma unroll
        for (int r = 0; r < 4; r++) {
            const int row = row0 + w * 16 + fq * 4 + r;
            const float v = acc[nb][r];
            const ushort_t o = dual ? f2b(v * 2.f * sigm_f(acc2[nb][r] + bb))
                                    : f2b(phi_f(v));
            outp[(size_t)row * 512 + col] = o;
        }
    }
}

// ---------------------------------------------------------------------------
// Output projection: out[4096,512] fp32 = nb(bf16) @ Wo^T, double-buffered
// ---------------------------------------------------------------------------
__global__ __launch_bounds__(256) void outproj_k(const ushort_t* __restrict__ A,
                                                 const ushort_t* __restrict__ Bt,
                                                 float* __restrict__ out) {
    __shared__ __align__(16) unsigned short As[2][4096];
    __shared__ __align__(16) unsigned short Bs[2][4096];
    const int tid = threadIdx.x;
    const int row0 = blockIdx.x * 64, n0 = blockIdx.y * 64;
    const int w = tid >> 6, lane = tid & 63;
    const int cc = tid & 7, rr = tid >> 3;
    const int fm = lane & 15, fq = lane >> 4;
    const int la0 = (cc * 64 + (rr ^ cc)) * 8;
    const int la1 = (cc * 64 + ((rr + 32) ^ cc)) * 8;

    f32x4 acc[4];
#pragma unroll
    for (int i = 0; i < 4; i++) acc[i] = (f32x4){0.f, 0.f, 0.f, 0.f};

    const ushort_t* aptr = A  + (size_t)(row0 + rr) * 512 + cc * 8;
    const ushort_t* bptr = Bt + (size_t)(n0 + rr) * 512 + cc * 8;
    int4 ra0 = *(const int4*)(aptr);
    int4 ra1 = *(const int4*)(aptr + 32 * 512);
    int4 rb0 = *(const int4*)(bptr);
    int4 rb1 = *(const int4*)(bptr + 32 * 512);
    *(int4*)&As[0][la0] = ra0; *(int4*)&As[0][la1] = ra1;
    *(int4*)&Bs[0][la0] = rb0; *(int4*)&Bs[0][la1] = rb1;
    __syncthreads();

    for (int kti = 0; kti < 8; kti++) {
        const int buf = kti & 1;
        if (kti < 7) {
            const int off = (kti + 1) * 64;
            ra0 = *(const int4*)(aptr + off);
            ra1 = *(const int4*)(aptr + off + 32 * 512);
            rb0 = *(const int4*)(bptr + off);
            rb1 = *(const int4*)(bptr + off + 32 * 512);
        }
#pragma unroll
        for (int j = 0; j < 2; j++) {
            const int cu = j * 4 + fq;
            bf16x8 af = *(const bf16x8*)&As[buf][(cu * 64 + ((w * 16 + fm) ^ cu)) * 8];
#pragma unroll
            for (int nb = 0; nb < 4; nb++) {
                bf16x8 bv = *(const bf16x8*)&Bs[buf][(cu * 64 + ((nb * 16 + fm) ^ cu)) * 8];
                acc[nb] = __builtin_amdgcn_mfma_f32_16x16x32_bf16(af, bv, acc[nb], 0, 0, 0);
            }
        }
        if (kti < 7) {
            const int nb_ = buf ^ 1;
            *(int4*)&As[nb_][la0] = ra0; *(int4*)&As[nb_][la1] = ra1;
            *(int4*)&Bs[nb_][la0] = rb0; *(int4*)&Bs[nb_][la1] = rb1;
            __syncthreads();
        }
    }
#pragma unroll
    for (int nb = 0; nb < 4; nb++) {
        const int col = n0 + nb * 16 + fm;
#pragma unroll
        for (int r = 0; r < 4; r++) {
            const int row = row0 + w * 16 + fq * 4 + r;
            __builtin_nontemporal_store(acc[nb][r], &out[(size_t)row * 512 + col]);
        }
    }
}

// ---------------------------------------------------------------------------
// K2a: per-(b,h,chunk) RAW sums: kv[k][v] = sum_t kf[t][k]*vg[t][v]; ksum[k]
// ---------------------------------------------------------------------------
__global__ __launch_bounds__(256) void chunksum_k(const ushort_t* __restrict__ kb,
                                                  const ushort_t* __restrict__ vb,
                                                  float* __restrict__ kv,
                                                  float* __restrict__ ksum) {
    __shared__ __align__(16) float kf_c[64][68];
    __shared__ __align__(16) float vg_c[64][68];
    const int tid = threadIdx.x;
    const int bh = blockIdx.x, c = blockIdx.y;
    const int b = bh >> 3, h = bh & 7;
    const int r = tid >> 2, qq = tid & 3;
    {
        const size_t rowbase = ((size_t)(b * TDIM + c * 64 + r)) * 512 + h * 64 + qq * 16;
        bfu k0, k1, v0, v1;
        k0.i4 = *(const int4*)(kb + rowbase);
        k1.i4 = *(const int4*)(kb + rowbase + 8);
        v0.i4 = *(const int4*)(vb + rowbase);
        v1.i4 = *(const int4*)(vb + rowbase + 8);
#pragma unroll
        for (int j = 0; j < 8; j++) {
            kf_c[r][qq * 16 + j]     = b2f(k0.us[j]);
            kf_c[r][qq * 16 + 8 + j] = b2f(k1.us[j]);
            vg_c[r][qq * 16 + j]     = b2f(v0.us[j]);
            vg_c[r][qq * 16 + 8 + j] = b2f(v1.us[j]);
        }
    }
    __syncthreads();
    const int k0i = (tid >> 4) * 4;
    const int v0i = (tid & 15) * 4;
    float4 a4[4];
#pragma unroll
    for (int i = 0; i < 4; i++) a4[i] = make_float4(0.f, 0.f, 0.f, 0.f);
    for (int t = 0; t < 64; t++) {
        float4 kk4 = *(const float4*)&kf_c[t][k0i];
        float4 vv  = *(const float4*)&vg_c[t][v0i];
        FMA4(a4[0], kk4.x, vv); FMA4(a4[1], kk4.y, vv);
        FMA4(a4[2], kk4.z, vv); FMA4(a4[3], kk4.w, vv);
    }
    const size_t base = (size_t)(bh * 16 + c) * 64;
#pragma unroll
    for (int i = 0; i < 4; i++)
        *(float4*)(kv + (base + k0i + i) * 64 + v0i) = a4[i];
    if (tid < 64) {
        float s = 0.f;
        for (int t = 0; t < 64; t++) s += kf_c[t][tid];
        ksum[base + tid] = s;
    }
}

// ---------------------------------------------------------------------------
// FUSED (monolithic, R10 244.3us config) with ONE change: all att stores are
// full-line contiguous. Stream & diag tiles bounce through the dead sc LDS
// region (free after P3; per-wave row ownership = race-free write), then are
// read back row-contiguously: each 16-lane group stores 256B contiguous.
// Zero-fill re-indexed the same way. dynamic LDS = 70144 bytes
// ---------------------------------------------------------------------------
__global__ __launch_bounds__(256) void fused_k(const ushort_t* __restrict__ qb,
                                               const ushort_t* __restrict__ kb,
                                               const ushort_t* __restrict__ vb,
                                               const float* __restrict__ kvc,
                                               const float* __restrict__ ksum,
                                               ushort_t* __restrict__ nbo,
                                               float* __restrict__ att) {
    extern __shared__ __align__(16) char smem[];
    unsigned short* qs   = (unsigned short*)smem;            // 4096 elem
    unsigned short* ksb  = qs + 4096;                        // 2 x 4096
    unsigned short* vrow = ksb + 8192;                       // 64x72
    float* kvf  = (float*)(vrow + 64 * 72);                  // 64x68
    float* sc   = kvf + 64 * 68;                             // 64x68 (tf reuse in P4)
    float* kpre = sc + 64 * 68;                              // 64
    float* ps   = kpre + 64;                                 // 64x4
    float* inv_s = ps + 256;                                 // 64

    const int tid = threadIdx.x;
    const int bh = blockIdx.x;
    const int yy = (int)blockIdx.y;
    const int diag = (yy < 8) ? (15 - yy) : (yy - 8);  // balanced pairing (neutral, kept)
    const int tt0 = diag * 64;
    const int b = bh >> 3, h = bh & 7;
    const int w = tid >> 6, lane = tid & 63;
    const int fm = lane & 15, fq = lane >> 4;
    const int rr = tid >> 3, cc = tid & 7;
    const int la0 = (cc * 64 + (rr ^ cc)) * 8;
    const int la1 = (cc * 64 + ((rr + 32) ^ cc)) * 8;

    const ushort_t* kbase = kb + ((size_t)(b * TDIM + rr)) * 512 + h * 64 + cc * 8;

    // ---- P0: staging ----
    {
        const ushort_t* qptr = qb + ((size_t)(b * TDIM + tt0 + rr)) * 512 + h * 64 + cc * 8;
        *(int4*)&qs[la0] = *(const int4*)qptr;
        *(int4*)&qs[la1] = *(const int4*)(qptr + 32 * 512);
        const ushort_t* kptr = kbase + (size_t)tt0 * 512;
        *(int4*)&ksb[la0] = *(const int4*)kptr;
        *(int4*)&ksb[la1] = *(const int4*)(kptr + 32 * 512);
        // V rows coalesced
        const int r = tid >> 2, qq = tid & 3;
        const ushort_t* vptr = vb + ((size_t)(b * TDIM + tt0 + r)) * 512 + h * 64 + qq * 16;
        *(int4*)&vrow[r * 72 + qq * 16]     = *(const int4*)vptr;
        *(int4*)&vrow[r * 72 + qq * 16 + 8] = *(const int4*)(vptr + 8);
        // KVpre accumulate over raw chunk sums
        float4 a4[4];
#pragma unroll
        for (int u = 0; u < 4; u++) a4[u] = make_float4(0.f, 0.f, 0.f, 0.f);
        for (int c2 = 0; c2 < diag; c2++) {
            const float* p = kvc + (size_t)(bh * 16 + c2) * 4096 + r * 64 + qq * 16;
#pragma unroll
            for (int u = 0; u < 4; u++) {
                float4 x = *(const float4*)(p + 4 * u);
                a4[u].x += x.x; a4[u].y += x.y; a4[u].z += x.z; a4[u].w += x.w;
            }
        }
#pragma unroll
        for (int u = 0; u < 4; u++) *(float4*)&kvf[r * 68 + qq * 16 + 4 * u] = a4[u];
        if (tid < 64) {
            float s = 0.f;
            for (int c2 = 0; c2 < diag; c2++)
                s += ksum[(size_t)(bh * 16 + c2) * 64 + tid];
            kpre[tid] = s;
        }
    }
    __syncthreads();

    // ---- P1: diag S = Q.K^T (keep sa in regs); prefetch att chunk 0 ----
    f32x4 sa[4];
    {
        int4 rk0 = {0,0,0,0}, rk1 = {0,0,0,0};
        if (diag > 0) {
            rk0 = *(const int4*)(kbase);
            rk1 = *(const int4*)(kbase + 32 * 512);
        }
#pragma unroll
        for (int i = 0; i < 4; i++) sa[i] = (f32x4){0.f, 0.f, 0.f, 0.f};
#pragma unroll
        for (int j = 0; j < 2; j++) {
            const int cu = j * 4 + fq;
            bf16x8 aqf = *(const bf16x8*)&qs[(cu * 64 + ((w * 16 + fm) ^ cu)) * 8];
#pragma unroll
            for (int nb = 0; nb < 4; nb++) {
                bf16x8 bk = *(const bf16x8*)&ksb[(cu * 64 + ((nb * 16 + fm) ^ cu)) * 8];
                sa[nb] = __builtin_amdgcn_mfma_f32_16x16x32_bf16(aqf, bk, sa[nb], 0, 0, 0);
            }
        }
#pragma unroll
        for (int nb = 0; nb < 4; nb++) {
            const int s_l = nb * 16 + fm;
#pragma unroll
            for (int r = 0; r < 4; r++) {
                const int t_l = w * 16 + fq * 4 + r;
                sc[t_l * 68 + s_l] = (s_l <= t_l) ? sa[nb][r] : 0.f;
            }
        }
        if (diag > 0) {
            *(int4*)&ksb[4096 + la0] = rk0;
            *(int4*)&ksb[4096 + la1] = rk1;
        }
    }
    __syncthreads();

    // ---- P2: denom -> inv_s ----
    {
        const int rw = tid >> 2, sq = tid & 3;
        float p = 0.f;
#pragma unroll
        for (int s = sq * 16; s < sq * 16 + 16; s++) p += sc[rw * 68 + s];
#pragma unroll
        for (int kd = sq * 16; kd < sq * 16 + 16; kd++) {
            const int cu = kd >> 3;
            p += b2f(qs[(cu * 64 + (rw ^ cu)) * 8 + (kd & 7)]) * kpre[kd];
        }
        ps[rw * 4 + sq] = p;
    }
    __syncthreads();
    {
        const int rw = tid >> 2, sq = tid & 3;
        if (sq == 0) {
            float den = ps[rw * 4] + ps[rw * 4 + 1] + ps[rw * 4 + 2] + ps[rw * 4 + 3];
            inv_s[rw] = 1.f / (den + EPSF);
        }
    }
    __syncthreads();

    // ---- P3: numer = Q.KVpre^T + P.V^T, scaled; write nbo bf16 ----
    {
        f32x4 oa[4];
#pragma unroll
        for (int i = 0; i < 4; i++) oa[i] = (f32x4){0.f, 0.f, 0.f, 0.f};
        bf16x8 aqv[2], apv[2];
#pragma unroll
        for (int j = 0; j < 2; j++) {
            const int cu = j * 4 + fq;
            aqv[j] = *(const bf16x8*)&qs[(cu * 64 + ((w * 16 + fm) ^ cu)) * 8];
            bfu t;
#pragma unroll
            for (int e2 = 0; e2 < 8; e2++) t.us[e2] = f2b(sc[(w * 16 + fm) * 68 + cu * 8 + e2]);
            apv[j] = t.v;
        }
#pragma unroll
        for (int nb = 0; nb < 4; nb++) {
            const int v = nb * 16 + fm;
#pragma unroll
            for (int j = 0; j < 2; j++) {
                const int cu = j * 4 + fq;
                bfu tkv, tv;
#pragma unroll
                for (int e = 0; e < 8; e++) {
                    tkv.us[e] = f2b(kvf[(cu * 8 + e) * 68 + v]);
                    tv.us[e]  = vrow[(cu * 8 + e) * 72 + v];
                }
                oa[nb] = __builtin_amdgcn_mfma_f32_16x16x32_bf16(aqv[j], tkv.v, oa[nb], 0, 0, 0);
                oa[nb] = __builtin_amdgcn_mfma_f32_16x16x32_bf16(apv[j], tv.v, oa[nb], 0, 0, 0);
            }
        }
#pragma unroll
        for (int nb = 0; nb < 4; nb++) {
            const int vcol = nb * 16 + fm;
#pragma unroll
            for (int r = 0; r < 4; r++) {
                const int t_l = w * 16 + fq * 4 + r;
                const float val = oa[nb][r] * inv_s[t_l];
                nbo[((size_t)(b * TDIM + tt0 + t_l)) * 512 + h * 64 + vcol] = f2b(val);
            }
        }
    }

    // ---- P4: att_map row of tiles (tf = sc, row-contiguous stores) ----
    bf16x8 aq[2];
    float invr[4];
#pragma unroll
    for (int j = 0; j < 2; j++) {
        const int cu = j * 4 + fq;
        aq[j] = *(const bf16x8*)&qs[(cu * 64 + ((w * 16 + fm) ^ cu)) * 8];
    }
#pragma unroll
    for (int r = 0; r < 4; r++) invr[r] = inv_s[w * 16 + fq * 4 + r];

    const int tr = tid >> 4, c4 = (tid & 15) * 4;   // readback indexing
    float* attb = att + (size_t)bh * TDIM * TDIM;
    int4 rk0, rk1;
    for (int st = 0; st < diag; st++) {
        const int bsel = (st + 1) & 1;  // st=0 -> ksb[1]
        if (st + 1 < diag) {
            const size_t off = (size_t)(st + 1) * 64 * 512;
            rk0 = *(const int4*)(kbase + off);
            rk1 = *(const int4*)(kbase + off + 32 * 512);
        }
        f32x4 pa[4];
#pragma unroll
        for (int i = 0; i < 4; i++) pa[i] = (f32x4){0.f, 0.f, 0.f, 0.f};
#pragma unroll
        for (int j = 0; j < 2; j++) {
            const int cu = j * 4 + fq;
#pragma unroll
            for (int nb = 0; nb < 4; nb++) {
                bf16x8 bk = *(const bf16x8*)&ksb[bsel * 4096 +
                                                 (cu * 64 + ((nb * 16 + fm) ^ cu)) * 8];
                pa[nb] = __builtin_amdgcn_mfma_f32_16x16x32_bf16(aq[j], bk, pa[nb], 0, 0, 0);
            }
        }
        // scale + park in tf (each wave writes only its own 16 rows)
#pragma unroll
        for (int nb = 0; nb < 4; nb++) {
            const int s_l = nb * 16 + fm;
#pragma unroll
            for (int r = 0; r < 4; r++) {
                const int t_l = w * 16 + fq * 4 + r;
                sc[t_l * 68 + s_l] = pa[nb][r] * invr[r];
            }
        }
        __syncthreads();
        // row-contiguous NT store (16 lanes x 16B = 256B per row-group)
        {
            const int s0 = st * 64;
#pragma unroll
            for (int p = 0; p < 4; p++) {
                const int row = p * 16 + tr;
                f32x4 v = *(f32x4*)&sc[row * 68 + c4];
                __builtin_nontemporal_store(v,
                    (f32x4*)&attb[(size_t)(tt0 + row) * TDIM + s0 + c4]);
            }
        }
        if (st + 1 < diag) {
            *(int4*)&ksb[(bsel ^ 1) * 4096 + la0] = rk0;
            *(int4*)&ksb[(bsel ^ 1) * 4096 + la1] = rk1;
        }
        __syncthreads();
    }
    // diagonal tile from sa (regs) via tf
#pragma unroll
    for (int nb = 0; nb < 4; nb++) {
        const int s_l = nb * 16 + fm;
#pragma unroll
        for (int r = 0; r < 4; r++) {
            const int t_l = w * 16 + fq * 4 + r;
            sc[t_l * 68 + s_l] = (s_l <= t_l) ? sa[nb][r] * invr[r] : 0.f;
        }
    }
    __syncthreads();
    {
#pragma unroll
        for (int p = 0; p < 4; p++) {
            const int row = p * 16 + tr;
            f32x4 v = *(f32x4*)&sc[row * 68 + c4];
            __builtin_nontemporal_store(v,
                (f32x4*)&attb[(size_t)(tt0 + row) * TDIM + tt0 + c4]);
        }
    }
    // zero-fill right of diagonal, row-contiguous (16 lanes per row)
    {
        const f32x4 z = (f32x4){0.f, 0.f, 0.f, 0.f};
        const int cstart = (diag + 1) * 64 + c4;
#pragma unroll
        for (int p = 0; p < 4; p++) {
            float* rowp = attb + (size_t)(tt0 + p * 16 + tr) * TDIM;
            for (int c0 = cstart; c0 < TDIM; c0 += 64)
                __builtin_nontemporal_store(z, (f32x4*)(rowp + c0));
        }
    }
}

// ---------------------------------------------------------------------------
extern "C" void kernel_launch(void* const* d_in, const int* in_sizes, int n_in,
                              void* d_out, int out_size, void* d_ws, size_t ws_size,
                              hipStream_t stream) {
    (void)in_sizes; (void)n_in; (void)out_size; (void)ws_size;
    const float* query = (const float*)d_in[0];
    const float* key   = (const float*)d_in[1];
    const float* value = (const float*)d_in[2];
    const float* Wq    = (const float*)d_in[3];
    const float* Wk    = (const float*)d_in[4];
    const float* Wv    = (const float*)d_in[5];
    const float* Wg    = (const float*)d_in[6];
    const float* bg    = (const float*)d_in[7];
    const float* Wo    = (const float*)d_in[8];
    float* out = (float*)d_out;                  // [B,T,M]
    float* att = (float*)d_out + 2097152;        // [B,H,T,T]
    float* ws  = (float*)d_ws;
    float* ksum = ws + OFF_KSUM;
    float* kv   = ws + OFF_KV;
    ushort_t* ub  = (ushort_t*)((char*)d_ws + FLOAT_BYTES);
    ushort_t* qp  = ub + UOFF_QP;
    ushort_t* kp  = ub + UOFF_KP;
    ushort_t* vp  = ub + UOFF_VP;
    ushort_t* nbp = ub + UOFF_NB;
    ushort_t* wqt = ub + UOFF_WQ;
    ushort_t* wkt = ub + UOFF_WK;
    ushort_t* wvt = ub + UOFF_WV;
    ushort_t* wgt = ub + UOFF_WG;
    ushort_t* wot = ub + UOFF_WO;

    dim3 blk(256);
    castwt_all<<<dim3(16, 16, 5), blk, 0, stream>>>(Wq, Wk, Wv, Wg, Wo,
                                                    wqt, wkt, wvt, wgt, wot);
    proj_k<<<dim3(64, 8, 3), blk, 0, stream>>>(query, key, value,
                                               wqt, wkt, wvt, wgt, bg, qp, kp, vp);
    chunksum_k<<<dim3(32, 16), blk, 0, stream>>>(kp, vp, kv, ksum);
    fused_k<<<dim3(32, 16), blk, 70144, stream>>>(qp, kp, vp, kv, ksum, nbp, att);
    outproj_k<<<dim3(64, 8), blk, 0, stream>>>(nbp, wot, out);
}